// Round 1
// baseline (582.651 us; speedup 1.0000x reference)
//
#include <hip/hip_runtime.h>

// Problem constants
// B=8, NGRID=4096, NOBS=4096, NPER=32, NLAYER=32, NC=50, SIGMA_SQ=1
#define kG 4096
#define kO 4096
#define kB 8
#define kP 32
#define kL 32
#define kNC 50

typedef short bf16x8 __attribute__((ext_vector_type(8)));
typedef float f32x4 __attribute__((ext_vector_type(4)));
typedef unsigned short u16x4 __attribute__((ext_vector_type(4)));

__device__ __forceinline__ unsigned short f2bf(float x) {
    unsigned u = __builtin_bit_cast(unsigned, x);
    u = (u + 0x7FFFu + ((u >> 16) & 1u)) >> 16;
    return (unsigned short)u;
}
__device__ __forceinline__ float bf2f(unsigned short b) {
    unsigned u = ((unsigned)b) << 16;
    return __builtin_bit_cast(float, u);
}

// ---------------- A -> A_hi, A_lo (bf16 split, natural layout) ----------------
__global__ void k_prep(const float* __restrict__ A, unsigned short* __restrict__ Ahi,
                       unsigned short* __restrict__ Alo) {
    const size_t i0 = ((size_t)blockIdx.x * 256 + threadIdx.x) * 4;
    float4 v = *(const float4*)(A + i0);
    float vv[4] = {v.x, v.y, v.z, v.w};
    u16x4 h, l;
    #pragma unroll
    for (int q = 0; q < 4; ++q) {
        unsigned short hb = f2bf(vv[q]);
        h[q] = hb;
        l[q] = f2bf(vv[q] - bf2f(hb));
    }
    *(u16x4*)(Ahi + i0) = h;
    *(u16x4*)(Alo + i0) = l;
}

// ---------------- s_true^T (n=b*32+p, g) bf16 split ----------------
__global__ void k_strue(const float* __restrict__ c_true, unsigned short* __restrict__ Sh,
                        unsigned short* __restrict__ Sl) {
    const int idx = blockIdx.x * 256 + threadIdx.x;   // n*4096 + g
    const int n = idx >> 12, g = idx & 4095;
    const int b = n >> 5, p = n & 31;
    float s = 1.0f / c_true[((size_t)(b * kG + g)) * kP + p];
    unsigned short hb = f2bf(s);
    Sh[idx] = hb;
    Sl[idx] = f2bf(s - bf2f(hb));
}

// ---------------- emax + logZ per (o,p) ----------------
__global__ void k_emax(const float* __restrict__ E, const float* __restrict__ cax,
                       float* __restrict__ emax, float* __restrict__ logZ) {
    const int o = blockIdx.x * 8 + (threadIdx.x >> 5);
    const int p = threadIdx.x & 31;
    const float* e = E + (size_t)o * kNC * kP + p;
    float m = -1e30f;
    for (int c = 0; c < kNC; ++c) m = fmaxf(m, e[c * kP]);
    const float* ax = cax + o * kNC;
    float Z = 0.f;
    float prevI = __expf(e[0] - m);
    float prevx = ax[0];
    for (int c = 1; c < kNC; ++c) {
        float I = __expf(e[c * kP] - m);
        float x = ax[c];
        Z += 0.5f * (prevI + I) * (x - prevx);
        prevI = I; prevx = x;
    }
    emax[o * kP + p] = m;
    logZ[o * kP + p] = __logf(Z + 1e-30f);
}

// ---------------- NT-GEMM: out[m,c] (+)= sum_k Pm[m,k]*Qm[c,k] ----------------
// M=256, N=4096, K=4096. grid = 64 c-tiles x 4 k-parts. 512 thr = 8 waves,
// wave tile 32m x 64c, MFMA 16x16x32 bf16, frags read straight from global.
template<int ACCUM>
__global__ __launch_bounds__(512) void k_gemm(const unsigned short* __restrict__ Pm,
                                              const unsigned short* __restrict__ Qm,
                                              float* __restrict__ outb) {
    const int kpart = blockIdx.x & 3;
    const int ct = blockIdx.x >> 2;
    const int c0 = ct * 64;
    const int wave = threadIdx.x >> 6;
    const int lane = threadIdx.x & 63;
    const int m0 = wave * 32;
    const int lrow = lane & 15;
    const int lk = (lane >> 4) << 3;
    const size_t k0 = (size_t)(kpart << 10) + lk;

    const unsigned short* pa = Pm + (size_t)(m0 + lrow) * 4096 + k0;
    const unsigned short* pb = Qm + (size_t)(c0 + lrow) * 4096 + k0;

    f32x4 acc[2][4];
    #pragma unroll
    for (int i = 0; i < 2; ++i)
        #pragma unroll
        for (int j = 0; j < 4; ++j) acc[i][j] = (f32x4){0.f, 0.f, 0.f, 0.f};

    #pragma unroll 4
    for (int kk = 0; kk < 32; ++kk) {
        const int off = kk << 5;
        bf16x8 a0 = *(const bf16x8*)(pa + off);
        bf16x8 a1 = *(const bf16x8*)(pa + 16 * 4096 + off);
        bf16x8 b0 = *(const bf16x8*)(pb + off);
        bf16x8 b1 = *(const bf16x8*)(pb + 16 * 4096 + off);
        bf16x8 b2 = *(const bf16x8*)(pb + 32 * 4096 + off);
        bf16x8 b3 = *(const bf16x8*)(pb + 48 * 4096 + off);
        acc[0][0] = __builtin_amdgcn_mfma_f32_16x16x32_bf16(a0, b0, acc[0][0], 0, 0, 0);
        acc[0][1] = __builtin_amdgcn_mfma_f32_16x16x32_bf16(a0, b1, acc[0][1], 0, 0, 0);
        acc[0][2] = __builtin_amdgcn_mfma_f32_16x16x32_bf16(a0, b2, acc[0][2], 0, 0, 0);
        acc[0][3] = __builtin_amdgcn_mfma_f32_16x16x32_bf16(a0, b3, acc[0][3], 0, 0, 0);
        acc[1][0] = __builtin_amdgcn_mfma_f32_16x16x32_bf16(a1, b0, acc[1][0], 0, 0, 0);
        acc[1][1] = __builtin_amdgcn_mfma_f32_16x16x32_bf16(a1, b1, acc[1][1], 0, 0, 0);
        acc[1][2] = __builtin_amdgcn_mfma_f32_16x16x32_bf16(a1, b2, acc[1][2], 0, 0, 0);
        acc[1][3] = __builtin_amdgcn_mfma_f32_16x16x32_bf16(a1, b3, acc[1][3], 0, 0, 0);
    }

    float* out = outb + (size_t)kpart * (256 * 4096);
    const int rbase = (lane >> 4) << 2;
    #pragma unroll
    for (int i = 0; i < 2; ++i) {
        #pragma unroll
        for (int j = 0; j < 4; ++j) {
            const int col = c0 + j * 16 + lrow;
            #pragma unroll
            for (int q = 0; q < 4; ++q) {
                const int row = m0 + i * 16 + rbase + q;
                const size_t oi = (size_t)row * 4096 + col;
                if (ACCUM) out[oi] += acc[i][j][q];
                else       out[oi] = acc[i][j][q];
            }
        }
    }
}

// ---------------- interp + log_like + XT = bf16(dlogp_ds_pred^T) ----------------
__global__ void k_interp(const float* __restrict__ SP,
                         const float* __restrict__ E, const float* __restrict__ cax,
                         const float* __restrict__ emax, const float* __restrict__ logZ,
                         unsigned short* __restrict__ XT, float* __restrict__ loglike) {
    const int n = blockIdx.x >> 4;
    const int o = (blockIdx.x & 15) * 256 + threadIdx.x;
    const int b = n >> 5, p = n & 31;
    const size_t sidx = (size_t)n * 4096 + o;
    float s = SP[sidx] + SP[sidx + 1048576] + SP[sidx + 2097152] + SP[sidx + 3145728];
    float cp = 1.0f / s;
    const float* ax = cax + o * kNC;
    int lo = 0, hi = kNC;
    while (lo < hi) { int mid = (lo + hi) >> 1; if (ax[mid] < cp) lo = mid + 1; else hi = mid; }
    int bi = lo; if (bi < 1) bi = 1; if (bi > kNC - 1) bi = kNC - 1;
    float x0 = ax[bi - 1], x1 = ax[bi];
    float y0 = E[((size_t)o * kNC + bi - 1) * kP + p];
    float y1 = E[((size_t)o * kNC + bi) * kP + p];
    float invdx = 1.0f / (x1 - x0 + 1e-12f);
    float t = (cp - x0) * invdx;
    float epred = y0 + t * (y1 - y0);
    float dedc = (y1 - y0) * invdx;
    float term = (epred - emax[o * kP + p]) - logZ[o * kP + p];
    XT[sidx] = f2bf(-dedc * cp * cp);

    __shared__ float red[256];
    red[threadIdx.x] = term;
    __syncthreads();
    for (int st = 128; st > 0; st >>= 1) {
        if (threadIdx.x < st) red[threadIdx.x] += red[threadIdx.x + st];
        __syncthreads();
    }
    if (threadIdx.x == 0) atomicAdd(loglike + b, red[0] * (1.0f / 32.0f));
}

// ---------------- transpose A_hi -> AT (bf16) ----------------
__global__ void k_trans(const unsigned short* __restrict__ Ahi, unsigned short* __restrict__ AT) {
    __shared__ unsigned short tile[64][65];
    const int to = blockIdx.x >> 6;
    const int tg = blockIdx.x & 63;
    const int o0 = to * 64, g0 = tg * 64;
    const int r = threadIdx.x >> 6, c = threadIdx.x & 63;
    #pragma unroll
    for (int rr = r; rr < 64; rr += 4)
        tile[rr][c] = Ahi[(size_t)(o0 + rr) * 4096 + g0 + c];
    __syncthreads();
    #pragma unroll
    for (int rr = r; rr < 64; rr += 4)
        AT[(size_t)(g0 + rr) * 4096 + o0 + c] = tile[c][rr];
}

// ---------------- grad = J^T contraction + sumsq ----------------
__global__ void k_grad(const float* __restrict__ W, const float* __restrict__ c_true,
                       const float* __restrict__ J, float* __restrict__ gout,
                       float* __restrict__ normsq) {
    __shared__ float wsm[8][32];
    __shared__ float red[256];
    const int b = blockIdx.x >> 9;
    const int g0 = (blockIdx.x & 511) * 8;
    const int gq = threadIdx.x >> 5;   // 0..7
    const int l = threadIdx.x & 31;
    {
        const int p = l;
        const int g = g0 + gq;
        const size_t widx = ((size_t)(b * 32 + p)) * 4096 + g;
        float w = W[widx] + W[widx + 1048576] + W[widx + 2097152] + W[widx + 3145728];
        float ct = c_true[((size_t)(b * kG + g)) * kP + p];
        wsm[gq][p] = -w / (ct * ct);
    }
    __syncthreads();
    const int g = g0 + gq;
    const float* jrow = J + (((size_t)(b * kG + g)) * kP) * kL + l;
    float acc = 0.f;
    #pragma unroll
    for (int p = 0; p < 32; ++p) acc += wsm[gq][p] * jrow[p * kL];
    gout[((size_t)(b * kG + g)) * kL + l] = acc;

    red[threadIdx.x] = acc * acc;
    __syncthreads();
    for (int st = 128; st > 0; st >>= 1) {
        if (threadIdx.x < st) red[threadIdx.x] += red[threadIdx.x + st];
        __syncthreads();
    }
    if (threadIdx.x == 0) atomicAdd(normsq + b, red[0]);
}

// ---------------- clip ----------------
__global__ void k_clip(float* __restrict__ gout, const float* __restrict__ normsq) {
    const int i = blockIdx.x * 256 + threadIdx.x;
    const int b = i >> 17;
    float norm = sqrtf(normsq[b]);
    float scale = norm > 1000.0f ? 1000.0f / norm : 1.0f;
    gout[i] *= scale;
}

extern "C" void kernel_launch(void* const* d_in, const int* in_sizes, int n_in,
                              void* d_out, int out_size, void* d_ws, size_t ws_size,
                              hipStream_t stream) {
    (void)in_sizes; (void)n_in; (void)out_size; (void)ws_size;
    const float* A      = (const float*)d_in[0];
    const float* c_true = (const float*)d_in[1];
    const float* J      = (const float*)d_in[2];
    const float* E_obs  = (const float*)d_in[3];
    const float* c_axis = (const float*)d_in[4];
    float* out = (float*)d_out;

    char* ws = (char*)d_ws;
    unsigned short* Ahi  = (unsigned short*)(ws);                 // 33,554,432 B
    unsigned short* Alo  = (unsigned short*)(ws + 33554432);      // 33,554,432 (reused as AT)
    unsigned short* AT   = Alo;
    unsigned short* Sthi = (unsigned short*)(ws + 67108864);      // 2,097,152
    unsigned short* Stlo = (unsigned short*)(ws + 69206016);      // 2,097,152
    unsigned short* XT   = (unsigned short*)(ws + 71303168);      // 2,097,152
    float* SP     = (float*)(ws + 73400320);                      // 16,777,216 (4 k-parts)
    float* Wb     = (float*)(ws + 90177536);                      // 16,777,216 (4 k-parts)
    float* emax   = (float*)(ws + 106954752);                     // 524,288
    float* logZ   = (float*)(ws + 107479040);                     // 524,288
    float* normsq = (float*)(ws + 108003328);                     // 32

    hipMemsetAsync(out, 0, 8 * sizeof(float), stream);
    hipMemsetAsync(normsq, 0, 8 * sizeof(float), stream);

    k_prep<<<16384, 256, 0, stream>>>(A, Ahi, Alo);
    k_strue<<<4096, 256, 0, stream>>>(c_true, Sthi, Stlo);
    k_emax<<<512, 256, 0, stream>>>(E_obs, c_axis, emax, logZ);

    // s_pred^T = (S_hi+S_lo) x (A_hi+A_lo), 3-term split-bf16 for ~fp32 accuracy
    k_gemm<0><<<256, 512, 0, stream>>>(Sthi, Ahi, SP);
    k_gemm<1><<<256, 512, 0, stream>>>(Stlo, Ahi, SP);
    k_gemm<1><<<256, 512, 0, stream>>>(Sthi, Alo, SP);

    k_interp<<<4096, 256, 0, stream>>>(SP, E_obs, c_axis, emax, logZ, XT, out);

    k_trans<<<4096, 256, 0, stream>>>(Ahi, AT);   // overwrites Alo (no longer needed)
    k_gemm<0><<<256, 512, 0, stream>>>(XT, AT, Wb);

    k_grad<<<4096, 256, 0, stream>>>(Wb, c_true, J, out + 8, normsq);
    k_clip<<<4096, 256, 0, stream>>>(out + 8, normsq);
}

// Round 3
// 526.847 us; speedup vs baseline: 1.1059x; 1.1059x over previous
//
#include <hip/hip_runtime.h>

// B=8, NGRID=4096, NOBS=4096, NPER=32, NLAYER=32, NC=50, SIGMA_SQ=1
#define kG 4096
#define kP 32
#define kL 32
#define kNC 50

typedef short bf16x8 __attribute__((ext_vector_type(8)));
typedef float f32x4 __attribute__((ext_vector_type(4)));
typedef unsigned short u16x4 __attribute__((ext_vector_type(4)));
typedef unsigned short u16x8 __attribute__((ext_vector_type(8)));

__device__ __forceinline__ unsigned short f2bf(float x) {
    unsigned u = __builtin_bit_cast(unsigned, x);
    u = (u + 0x7FFFu + ((u >> 16) & 1u)) >> 16;
    return (unsigned short)u;
}
__device__ __forceinline__ float bf2f(unsigned short b) {
    unsigned u = ((unsigned)b) << 16;
    return __builtin_bit_cast(float, u);
}

// ---------------- A -> A_hi, A_lo (natural) + AT_hi (transposed), one pass ----------------
__global__ __launch_bounds__(256) void k_prep(const float* __restrict__ A,
        unsigned short* __restrict__ Ah, unsigned short* __restrict__ Al,
        unsigned short* __restrict__ AT) {
    __shared__ unsigned short tile[64][68];
    const int to = blockIdx.x >> 6, tg = blockIdx.x & 63;
    const int o0 = to << 6, g0 = tg << 6;
    const int tr = threadIdx.x >> 4;          // 0..15
    const int c4 = (threadIdx.x & 15) << 2;   // 0..60
    #pragma unroll
    for (int rr = tr; rr < 64; rr += 16) {
        float4 v = *(const float4*)(A + (size_t)(o0 + rr) * 4096 + g0 + c4);
        float vv[4] = {v.x, v.y, v.z, v.w};
        u16x4 h, l;
        #pragma unroll
        for (int q = 0; q < 4; ++q) {
            unsigned short hb = f2bf(vv[q]);
            h[q] = hb;
            l[q] = f2bf(vv[q] - bf2f(hb));
            tile[rr][c4 + q] = hb;
        }
        *(u16x4*)(Ah + (size_t)(o0 + rr) * 4096 + g0 + c4) = h;
        *(u16x4*)(Al + (size_t)(o0 + rr) * 4096 + g0 + c4) = l;
    }
    __syncthreads();
    #pragma unroll
    for (int rr = tr; rr < 64; rr += 16) {
        u16x4 tv;
        #pragma unroll
        for (int q = 0; q < 4; ++q) tv[q] = tile[c4 + q][rr];
        *(u16x4*)(AT + (size_t)(g0 + rr) * 4096 + o0 + c4) = tv;
    }
}

// ---------------- s_true^T (n=b*32+p, g) bf16 split, coalesced via LDS transpose ----------------
__global__ __launch_bounds__(256) void k_strue(const float* __restrict__ c_true,
        unsigned short* __restrict__ Sh, unsigned short* __restrict__ Sl) {
    __shared__ float sm[32][65];
    const int b = blockIdx.x >> 6;
    const int g0 = (blockIdx.x & 63) << 6;
    const int gl = threadIdx.x >> 5;   // 0..7
    const int p = threadIdx.x & 31;
    #pragma unroll
    for (int gg = gl; gg < 64; gg += 8) {
        float c = c_true[((size_t)(b << 12) + g0 + gg) * 32 + p];
        sm[p][gg] = 1.0f / c;
    }
    __syncthreads();
    const int p2 = threadIdx.x >> 3;          // 0..31
    const int gq = (threadIdx.x & 7) << 3;    // 0..56
    u16x8 h, l;
    #pragma unroll
    for (int q = 0; q < 8; ++q) {
        float s = sm[p2][gq + q];
        unsigned short hb = f2bf(s);
        h[q] = hb;
        l[q] = f2bf(s - bf2f(hb));
    }
    const size_t oidx = (size_t)(b * 32 + p2) * 4096 + g0 + gq;
    *(u16x8*)(Sh + oidx) = h;
    *(u16x8*)(Sl + oidx) = l;
}

// ---------------- emax + logZ per (o,p) ----------------
__global__ __launch_bounds__(256) void k_emax(const float* __restrict__ E, const float* __restrict__ cax,
                       float* __restrict__ emax, float* __restrict__ logZ) {
    const int o = blockIdx.x * 8 + (threadIdx.x >> 5);
    const int p = threadIdx.x & 31;
    const float* e = E + (size_t)o * kNC * kP + p;
    float m = -1e30f;
    for (int c = 0; c < kNC; ++c) m = fmaxf(m, e[c * kP]);
    const float* ax = cax + o * kNC;
    float Z = 0.f;
    float prevI = __expf(e[0] - m);
    float prevx = ax[0];
    for (int c = 1; c < kNC; ++c) {
        float I = __expf(e[c * kP] - m);
        float x = ax[c];
        Z += 0.5f * (prevI + I) * (x - prevx);
        prevI = I; prevx = x;
    }
    emax[o * kP + p] = m;
    logZ[o * kP + p] = __logf(Z + 1e-30f);
}

// ---------------- NT-GEMM: out[part][m][c] = sum_k P[m,k]*Q[c,k] (3-term split if SPLIT) ----------------
// M=256, N=4096, K=4096. grid = 64 c-tiles x 8 k-parts = 512 blocks (2/CU),
// 512 thr = 8 waves, wave tile 32m x 64c, MFMA 16x16x32 bf16, frags from global.
template<int SPLIT>
__global__ __launch_bounds__(512, 4) void k_nt(const unsigned short* __restrict__ Ph,
        const unsigned short* __restrict__ Pl, const unsigned short* __restrict__ Qh,
        const unsigned short* __restrict__ Ql, float* __restrict__ outb) {
    const int kpart = blockIdx.x & 7;          // aligns k-part <-> XCD for L2 locality
    const int ct = blockIdx.x >> 3;
    const int c0 = ct << 6;
    const int wave = threadIdx.x >> 6;
    const int lane = threadIdx.x & 63;
    const int m0 = wave << 5;
    const int lrow = lane & 15;
    const int lk = (lane >> 4) << 3;
    const size_t koff = ((size_t)kpart << 9) + lk;

    const unsigned short* pah = Ph + (size_t)(m0 + lrow) * 4096 + koff;
    const unsigned short* pbh = Qh + (size_t)(c0 + lrow) * 4096 + koff;
    const unsigned short* pal = Pl + (size_t)(m0 + lrow) * 4096 + koff;
    const unsigned short* pbl = Ql + (size_t)(c0 + lrow) * 4096 + koff;

    f32x4 acc[2][4];
    #pragma unroll
    for (int i = 0; i < 2; ++i)
        #pragma unroll
        for (int j = 0; j < 4; ++j) acc[i][j] = (f32x4){0.f, 0.f, 0.f, 0.f};

    #pragma unroll 4
    for (int kk = 0; kk < 16; ++kk) {
        const int off = kk << 5;
        bf16x8 a0 = *(const bf16x8*)(pah + off);
        bf16x8 a1 = *(const bf16x8*)(pah + 16 * 4096 + off);
        bf16x8 b0 = *(const bf16x8*)(pbh + off);
        bf16x8 b1 = *(const bf16x8*)(pbh + 16 * 4096 + off);
        bf16x8 b2 = *(const bf16x8*)(pbh + 32 * 4096 + off);
        bf16x8 b3 = *(const bf16x8*)(pbh + 48 * 4096 + off);
        acc[0][0] = __builtin_amdgcn_mfma_f32_16x16x32_bf16(a0, b0, acc[0][0], 0, 0, 0);
        acc[0][1] = __builtin_amdgcn_mfma_f32_16x16x32_bf16(a0, b1, acc[0][1], 0, 0, 0);
        acc[0][2] = __builtin_amdgcn_mfma_f32_16x16x32_bf16(a0, b2, acc[0][2], 0, 0, 0);
        acc[0][3] = __builtin_amdgcn_mfma_f32_16x16x32_bf16(a0, b3, acc[0][3], 0, 0, 0);
        acc[1][0] = __builtin_amdgcn_mfma_f32_16x16x32_bf16(a1, b0, acc[1][0], 0, 0, 0);
        acc[1][1] = __builtin_amdgcn_mfma_f32_16x16x32_bf16(a1, b1, acc[1][1], 0, 0, 0);
        acc[1][2] = __builtin_amdgcn_mfma_f32_16x16x32_bf16(a1, b2, acc[1][2], 0, 0, 0);
        acc[1][3] = __builtin_amdgcn_mfma_f32_16x16x32_bf16(a1, b3, acc[1][3], 0, 0, 0);
        if (SPLIT) {
            bf16x8 a0l = *(const bf16x8*)(pal + off);
            bf16x8 a1l = *(const bf16x8*)(pal + 16 * 4096 + off);
            bf16x8 c0v = *(const bf16x8*)(pbl + off);
            bf16x8 c1v = *(const bf16x8*)(pbl + 16 * 4096 + off);
            bf16x8 c2v = *(const bf16x8*)(pbl + 32 * 4096 + off);
            bf16x8 c3v = *(const bf16x8*)(pbl + 48 * 4096 + off);
            acc[0][0] = __builtin_amdgcn_mfma_f32_16x16x32_bf16(a0l, b0, acc[0][0], 0, 0, 0);
            acc[0][1] = __builtin_amdgcn_mfma_f32_16x16x32_bf16(a0l, b1, acc[0][1], 0, 0, 0);
            acc[0][2] = __builtin_amdgcn_mfma_f32_16x16x32_bf16(a0l, b2, acc[0][2], 0, 0, 0);
            acc[0][3] = __builtin_amdgcn_mfma_f32_16x16x32_bf16(a0l, b3, acc[0][3], 0, 0, 0);
            acc[1][0] = __builtin_amdgcn_mfma_f32_16x16x32_bf16(a1l, b0, acc[1][0], 0, 0, 0);
            acc[1][1] = __builtin_amdgcn_mfma_f32_16x16x32_bf16(a1l, b1, acc[1][1], 0, 0, 0);
            acc[1][2] = __builtin_amdgcn_mfma_f32_16x16x32_bf16(a1l, b2, acc[1][2], 0, 0, 0);
            acc[1][3] = __builtin_amdgcn_mfma_f32_16x16x32_bf16(a1l, b3, acc[1][3], 0, 0, 0);
            acc[0][0] = __builtin_amdgcn_mfma_f32_16x16x32_bf16(a0, c0v, acc[0][0], 0, 0, 0);
            acc[0][1] = __builtin_amdgcn_mfma_f32_16x16x32_bf16(a0, c1v, acc[0][1], 0, 0, 0);
            acc[0][2] = __builtin_amdgcn_mfma_f32_16x16x32_bf16(a0, c2v, acc[0][2], 0, 0, 0);
            acc[0][3] = __builtin_amdgcn_mfma_f32_16x16x32_bf16(a0, c3v, acc[0][3], 0, 0, 0);
            acc[1][0] = __builtin_amdgcn_mfma_f32_16x16x32_bf16(a1, c0v, acc[1][0], 0, 0, 0);
            acc[1][1] = __builtin_amdgcn_mfma_f32_16x16x32_bf16(a1, c1v, acc[1][1], 0, 0, 0);
            acc[1][2] = __builtin_amdgcn_mfma_f32_16x16x32_bf16(a1, c2v, acc[1][2], 0, 0, 0);
            acc[1][3] = __builtin_amdgcn_mfma_f32_16x16x32_bf16(a1, c3v, acc[1][3], 0, 0, 0);
        }
    }

    float* out = outb + (size_t)kpart * (256 * 4096);
    const int rbase = (lane >> 4) << 2;
    #pragma unroll
    for (int i = 0; i < 2; ++i) {
        #pragma unroll
        for (int j = 0; j < 4; ++j) {
            const int col = c0 + j * 16 + lrow;
            #pragma unroll
            for (int q = 0; q < 4; ++q) {
                const int row = m0 + i * 16 + rbase + q;
                out[(size_t)row * 4096 + col] = acc[i][j][q];
            }
        }
    }
}

// ---------------- interp + log_like + XT = bf16(dlogp_ds_pred^T) ----------------
__global__ __launch_bounds__(256) void k_interp(const float* __restrict__ SP,
                         const float* __restrict__ E, const float* __restrict__ cax,
                         const float* __restrict__ emax, const float* __restrict__ logZ,
                         unsigned short* __restrict__ XT, float* __restrict__ loglike) {
    const int n = blockIdx.x >> 4;
    const int o = (blockIdx.x & 15) * 256 + threadIdx.x;
    const int b = n >> 5, p = n & 31;
    const size_t sidx = (size_t)n * 4096 + o;
    float s = 0.f;
    #pragma unroll
    for (int part = 0; part < 8; ++part) s += SP[sidx + (size_t)part * 1048576];
    float cp = 1.0f / s;
    const float* ax = cax + o * kNC;
    int lo = 0, hi = kNC;
    while (lo < hi) { int mid = (lo + hi) >> 1; if (ax[mid] < cp) lo = mid + 1; else hi = mid; }
    int bi = lo; if (bi < 1) bi = 1; if (bi > kNC - 1) bi = kNC - 1;
    float x0 = ax[bi - 1], x1 = ax[bi];
    float y0 = E[((size_t)o * kNC + bi - 1) * kP + p];
    float y1 = E[((size_t)o * kNC + bi) * kP + p];
    float invdx = 1.0f / (x1 - x0 + 1e-12f);
    float t = (cp - x0) * invdx;
    float epred = y0 + t * (y1 - y0);
    float dedc = (y1 - y0) * invdx;
    float term = (epred - emax[o * kP + p]) - logZ[o * kP + p];
    XT[sidx] = f2bf(-dedc * cp * cp);

    __shared__ float red[256];
    red[threadIdx.x] = term;
    __syncthreads();
    for (int st = 128; st > 0; st >>= 1) {
        if (threadIdx.x < st) red[threadIdx.x] += red[threadIdx.x + st];
        __syncthreads();
    }
    if (threadIdx.x == 0) atomicAdd(loglike + b, red[0] * (1.0f / 32.0f));
}

// ---------------- grad = J^T contraction + sumsq ----------------
__global__ __launch_bounds__(256) void k_grad(const float* __restrict__ W, const float* __restrict__ c_true,
                       const float* __restrict__ J, float* __restrict__ gout,
                       float* __restrict__ normsq) {
    __shared__ float wsm[8][33];
    __shared__ float red[256];
    const int b = blockIdx.x >> 9;
    const int g0 = (blockIdx.x & 511) << 3;
    {   // coalesced W load: 8 consecutive g per 8 lanes, 32 p rows
        const int p = threadIdx.x >> 3, gq = threadIdx.x & 7;
        const size_t widx = (size_t)(b * 32 + p) * 4096 + g0 + gq;
        float w = 0.f;
        #pragma unroll
        for (int part = 0; part < 8; ++part) w += W[widx + (size_t)part * 1048576];
        float ct = c_true[((size_t)(b << 12) + g0 + gq) * 32 + p];
        wsm[gq][p] = -w / (ct * ct);
    }
    __syncthreads();
    const int gq = threadIdx.x >> 5;   // 0..7
    const int l = threadIdx.x & 31;
    const int g = g0 + gq;
    const float* jrow = J + ((size_t)(b << 12) + g) * (kP * kL) + l;
    float acc = 0.f;
    #pragma unroll
    for (int p = 0; p < 32; ++p) acc += wsm[gq][p] * jrow[p * kL];
    gout[((size_t)(b << 12) + g) * kL + l] = acc;

    red[threadIdx.x] = acc * acc;
    __syncthreads();
    for (int st = 128; st > 0; st >>= 1) {
        if (threadIdx.x < st) red[threadIdx.x] += red[threadIdx.x + st];
        __syncthreads();
    }
    if (threadIdx.x == 0) atomicAdd(normsq + b, red[0]);
}

// ---------------- clip ----------------
__global__ __launch_bounds__(256) void k_clip(float* __restrict__ gout, const float* __restrict__ normsq) {
    const int i = blockIdx.x * 256 + threadIdx.x;
    const int b = i >> 17;
    float norm = sqrtf(normsq[b]);
    float scale = norm > 1000.0f ? 1000.0f / norm : 1.0f;
    gout[i] *= scale;
}

extern "C" void kernel_launch(void* const* d_in, const int* in_sizes, int n_in,
                              void* d_out, int out_size, void* d_ws, size_t ws_size,
                              hipStream_t stream) {
    (void)in_sizes; (void)n_in; (void)out_size; (void)ws_size;
    const float* A      = (const float*)d_in[0];
    const float* c_true = (const float*)d_in[1];
    const float* J      = (const float*)d_in[2];
    const float* E_obs  = (const float*)d_in[3];
    const float* c_axis = (const float*)d_in[4];
    float* out = (float*)d_out;

    char* ws = (char*)d_ws;
    unsigned short* Ah   = (unsigned short*)(ws);                  // 32 MB
    unsigned short* Al   = (unsigned short*)(ws + 33554432);       // 32 MB
    unsigned short* AT   = (unsigned short*)(ws + 67108864);       // 32 MB
    unsigned short* Sh   = (unsigned short*)(ws + 100663296);      // 2 MB
    unsigned short* Sl   = (unsigned short*)(ws + 102760448);      // 2 MB
    unsigned short* XT   = (unsigned short*)(ws + 104857600);      // 2 MB
    float* SP     = (float*)(ws + 106954752);                      // 32 MB (8 k-parts)
    float* Wb     = (float*)(ws + 140509184);                      // 32 MB (8 k-parts)
    float* emax   = (float*)(ws + 174063616);                      // 512 KB
    float* logZ   = (float*)(ws + 174587904);                      // 512 KB
    float* normsq = (float*)(ws + 175112192);                      // 32 B

    hipMemsetAsync(out, 0, 8 * sizeof(float), stream);
    hipMemsetAsync(normsq, 0, 8 * sizeof(float), stream);

    k_prep<<<4096, 256, 0, stream>>>(A, Ah, Al, AT);
    k_strue<<<512, 256, 0, stream>>>(c_true, Sh, Sl);
    k_emax<<<512, 256, 0, stream>>>(E_obs, c_axis, emax, logZ);

    // s_pred^T: fused 3-term split-bf16 (S_hi·A_hi + S_lo·A_hi + S_hi·A_lo)
    k_nt<1><<<512, 512, 0, stream>>>(Sh, Sl, Ah, Al, SP);

    k_interp<<<4096, 256, 0, stream>>>(SP, E_obs, c_axis, emax, logZ, XT, out);

    // W^T = XT x AT (single bf16 term)
    k_nt<0><<<512, 512, 0, stream>>>(XT, XT, AT, AT, Wb);

    k_grad<<<4096, 256, 0, stream>>>(Wb, c_true, J, out + 8, normsq);
    k_clip<<<4096, 256, 0, stream>>>(out + 8, normsq);
}

// Round 4
// 429.841 us; speedup vs baseline: 1.3555x; 1.2257x over previous
//
#include <hip/hip_runtime.h>

// B=8, NGRID=4096, NOBS=4096, NPER=32, NLAYER=32, NC=50, SIGMA_SQ=1
#define kG 4096
#define kP 32
#define kL 32
#define kNC 50

typedef short bf16x8 __attribute__((ext_vector_type(8)));
typedef float f32x4 __attribute__((ext_vector_type(4)));
typedef unsigned short u16x4 __attribute__((ext_vector_type(4)));
typedef unsigned short u16x8 __attribute__((ext_vector_type(8)));

__device__ __forceinline__ unsigned short f2bf(float x) {
    unsigned u = __builtin_bit_cast(unsigned, x);
    u = (u + 0x7FFFu + ((u >> 16) & 1u)) >> 16;
    return (unsigned short)u;
}
__device__ __forceinline__ float bf2f(unsigned short b) {
    unsigned u = ((unsigned)b) << 16;
    return __builtin_bit_cast(float, u);
}

// async global->LDS, 16B per lane. LDS dest must be linear in lane order.
__device__ __forceinline__ void gload_lds16(const void* g, void* l) {
    __builtin_amdgcn_global_load_lds(
        (const __attribute__((address_space(1))) unsigned int*)g,
        (__attribute__((address_space(3))) unsigned int*)l, 16, 0, 0);
}

// ---------------- A -> A_hi, A_lo (natural) + AT_hi (transposed), one pass ----------------
__global__ __launch_bounds__(256) void k_prep(const float* __restrict__ A,
        unsigned short* __restrict__ Ah, unsigned short* __restrict__ Al,
        unsigned short* __restrict__ AT) {
    __shared__ unsigned short tile[64][68];
    const int to = blockIdx.x >> 6, tg = blockIdx.x & 63;
    const int o0 = to << 6, g0 = tg << 6;
    const int tr = threadIdx.x >> 4;          // 0..15
    const int c4 = (threadIdx.x & 15) << 2;   // 0..60
    #pragma unroll
    for (int rr = tr; rr < 64; rr += 16) {
        float4 v = *(const float4*)(A + (size_t)(o0 + rr) * 4096 + g0 + c4);
        float vv[4] = {v.x, v.y, v.z, v.w};
        u16x4 h, l;
        #pragma unroll
        for (int q = 0; q < 4; ++q) {
            unsigned short hb = f2bf(vv[q]);
            h[q] = hb;
            l[q] = f2bf(vv[q] - bf2f(hb));
            tile[rr][c4 + q] = hb;
        }
        *(u16x4*)(Ah + (size_t)(o0 + rr) * 4096 + g0 + c4) = h;
        *(u16x4*)(Al + (size_t)(o0 + rr) * 4096 + g0 + c4) = l;
    }
    __syncthreads();
    #pragma unroll
    for (int rr = tr; rr < 64; rr += 16) {
        u16x4 tv;
        #pragma unroll
        for (int q = 0; q < 4; ++q) tv[q] = tile[c4 + q][rr];
        *(u16x4*)(AT + (size_t)(g0 + rr) * 4096 + o0 + c4) = tv;
    }
}

// ---------------- s_true^T (n=b*32+p, g) bf16 split, coalesced via LDS transpose ----------------
__global__ __launch_bounds__(256) void k_strue(const float* __restrict__ c_true,
        unsigned short* __restrict__ Sh, unsigned short* __restrict__ Sl) {
    __shared__ float sm[32][65];
    const int b = blockIdx.x >> 6;
    const int g0 = (blockIdx.x & 63) << 6;
    const int gl = threadIdx.x >> 5;   // 0..7
    const int p = threadIdx.x & 31;
    #pragma unroll
    for (int gg = gl; gg < 64; gg += 8) {
        float c = c_true[((size_t)(b << 12) + g0 + gg) * 32 + p];
        sm[p][gg] = 1.0f / c;
    }
    __syncthreads();
    const int p2 = threadIdx.x >> 3;          // 0..31
    const int gq = (threadIdx.x & 7) << 3;    // 0..56
    u16x8 h, l;
    #pragma unroll
    for (int q = 0; q < 8; ++q) {
        float s = sm[p2][gq + q];
        unsigned short hb = f2bf(s);
        h[q] = hb;
        l[q] = f2bf(s - bf2f(hb));
    }
    const size_t oidx = (size_t)(b * 32 + p2) * 4096 + g0 + gq;
    *(u16x8*)(Sh + oidx) = h;
    *(u16x8*)(Sl + oidx) = l;
}

// ---------------- emax + logZ per (o,p) ----------------
__global__ __launch_bounds__(256) void k_emax(const float* __restrict__ E, const float* __restrict__ cax,
                       float* __restrict__ emax, float* __restrict__ logZ) {
    const int o = blockIdx.x * 8 + (threadIdx.x >> 5);
    const int p = threadIdx.x & 31;
    const float* e = E + (size_t)o * kNC * kP + p;
    float m = -1e30f;
    for (int c = 0; c < kNC; ++c) m = fmaxf(m, e[c * kP]);
    const float* ax = cax + o * kNC;
    float Z = 0.f;
    float prevI = __expf(e[0] - m);
    float prevx = ax[0];
    for (int c = 1; c < kNC; ++c) {
        float I = __expf(e[c * kP] - m);
        float x = ax[c];
        Z += 0.5f * (prevI + I) * (x - prevx);
        prevI = I; prevx = x;
    }
    emax[o * kP + p] = m;
    logZ[o * kP + p] = __logf(Z + 1e-30f);
}

// ---------------- LDS-staged NT-GEMM ----------------
// C[part][m][n] = sum_k P[m,k]*Q[n,k], M=256, N=4096, K=4096, 3-term if SPLIT.
// BM=128, BN=128, BK=64, split-K=4 -> 256 blocks (1/CU), 512 thr = 8 waves
// (2m x 4n, wave-tile 64x32). Tiles staged via global_load_lds (16B) into
// double-buffered LDS with st-style XOR swizzle (both-sides: inverse-swizzled
// global source + swizzled ds_read). 2-phase pipeline: stage(next), compute(cur),
// barrier (compiler's vmcnt(0) drain sits after the compute phase).
template<int SPLIT>
__global__ __launch_bounds__(512, 2) void k_nt2(const unsigned short* __restrict__ Ph,
        const unsigned short* __restrict__ Pl, const unsigned short* __restrict__ Qh,
        const unsigned short* __restrict__ Ql, float* __restrict__ outb) {
    constexpr int NTIL = SPLIT ? 4 : 2;             // Ph,Qh[,Pl,Ql] 16KB tiles
    __shared__ __align__(16) unsigned short lds[2 * NTIL * 8192];

    const int bid = blockIdx.x;
    const int mt = bid & 1;
    const int kp = (bid >> 1) & 3;
    const int nt = bid >> 3;
    const int mbase = mt << 7;
    const int nbase = nt << 7;
    const int kbase = kp << 10;

    const int tid = threadIdx.x;
    const int lane = tid & 63;
    const int wid = tid >> 6;
    const int wm = wid >> 2;      // 0..1 : 64-row slice
    const int wn = wid & 3;       // 0..3 : 32-col slice
    const int lrow = lane & 15;
    const int kg = lane >> 4;

    // staging slots: physical 16B slot P -> logical L = P ^ (((P>>7)&7)<<4)
    int r_[2], ke_[2], Pb_[2];
    #pragma unroll
    for (int i = 0; i < 2; ++i) {
        int P = (tid + (i << 9)) << 4;
        int L = P ^ (((P >> 7) & 7) << 4);
        Pb_[i] = P;
        r_[i] = L >> 7;
        ke_[i] = (L & 127) >> 1;
    }

    auto stage = [&](unsigned short* t, const unsigned short* src, int rb, int k0) {
        #pragma unroll
        for (int i = 0; i < 2; ++i) {
            const unsigned short* g = src + (size_t)(rb + r_[i]) * 4096 + (k0 + ke_[i]);
            gload_lds16(g, (char*)t + Pb_[i]);
        }
    };
    auto stage_all = [&](int buf, int t) {
        const int k0 = kbase + (t << 6);
        unsigned short* base = lds + buf * (NTIL * 8192);
        stage(base, Ph, mbase, k0);
        stage(base + 8192, Qh, nbase, k0);
        if (SPLIT) {
            stage(base + 2 * 8192, Pl, mbase, k0);
            stage(base + 3 * 8192, Ql, nbase, k0);
        }
    };
    // swizzled fragment read: row r, k-element kc (8 bf16 = 16B)
    auto ldfrag = [&](const unsigned short* t, int r, int kc) -> bf16x8 {
        int L = (r << 7) + (kc << 1);
        int Pb = L ^ ((r & 7) << 4);
        return *(const bf16x8*)((const char*)t + Pb);
    };

    f32x4 acc[4][2];
    #pragma unroll
    for (int fi = 0; fi < 4; ++fi)
        #pragma unroll
        for (int fj = 0; fj < 2; ++fj) acc[fi][fj] = (f32x4){0.f, 0.f, 0.f, 0.f};

    auto compute = [&](int buf) {
        const unsigned short* tb = lds + buf * (NTIL * 8192);
        #pragma unroll
        for (int kk = 0; kk < 2; ++kk) {
            const int kc = (kk << 5) + (kg << 3);
            bf16x8 ah[4], bh[2];
            #pragma unroll
            for (int fi = 0; fi < 4; ++fi)
                ah[fi] = ldfrag(tb, (wm << 6) + (fi << 4) + lrow, kc);
            #pragma unroll
            for (int fj = 0; fj < 2; ++fj)
                bh[fj] = ldfrag(tb + 8192, (wn << 5) + (fj << 4) + lrow, kc);
            #pragma unroll
            for (int fi = 0; fi < 4; ++fi)
                #pragma unroll
                for (int fj = 0; fj < 2; ++fj)
                    acc[fi][fj] = __builtin_amdgcn_mfma_f32_16x16x32_bf16(ah[fi], bh[fj], acc[fi][fj], 0, 0, 0);
            if (SPLIT) {
                bf16x8 al[4], bl[2];
                #pragma unroll
                for (int fi = 0; fi < 4; ++fi)
                    al[fi] = ldfrag(tb + 2 * 8192, (wm << 6) + (fi << 4) + lrow, kc);
                #pragma unroll
                for (int fj = 0; fj < 2; ++fj)
                    bl[fj] = ldfrag(tb + 3 * 8192, (wn << 5) + (fj << 4) + lrow, kc);
                #pragma unroll
                for (int fi = 0; fi < 4; ++fi)
                    #pragma unroll
                    for (int fj = 0; fj < 2; ++fj) {
                        acc[fi][fj] = __builtin_amdgcn_mfma_f32_16x16x32_bf16(al[fi], bh[fj], acc[fi][fj], 0, 0, 0);
                        acc[fi][fj] = __builtin_amdgcn_mfma_f32_16x16x32_bf16(ah[fi], bl[fj], acc[fi][fj], 0, 0, 0);
                    }
            }
        }
    };

    stage_all(0, 0);
    __syncthreads();

    int buf = 0;
    #pragma unroll 1
    for (int t = 0; t < 15; ++t) {
        stage_all(buf ^ 1, t + 1);   // issue next-tile loads (in flight during compute)
        compute(buf);
        __syncthreads();             // compiler emits vmcnt(0) drain here
        buf ^= 1;
    }
    compute(buf);

    float* outp = outb + (size_t)kp * (256 * 4096);
    #pragma unroll
    for (int fi = 0; fi < 4; ++fi)
        #pragma unroll
        for (int fj = 0; fj < 2; ++fj) {
            const int col = nbase + (wn << 5) + (fj << 4) + lrow;
            #pragma unroll
            for (int q = 0; q < 4; ++q) {
                const int row = mbase + (wm << 6) + (fi << 4) + (kg << 2) + q;
                outp[(size_t)row * 4096 + col] = acc[fi][fj][q];
            }
        }
}

// ---------------- interp + log_like + XT = bf16(dlogp_ds_pred^T) ----------------
__global__ __launch_bounds__(256) void k_interp(const float* __restrict__ SP,
                         const float* __restrict__ E, const float* __restrict__ cax,
                         const float* __restrict__ emax, const float* __restrict__ logZ,
                         unsigned short* __restrict__ XT, float* __restrict__ loglike) {
    const int n = blockIdx.x >> 4;
    const int o = (blockIdx.x & 15) * 256 + threadIdx.x;
    const int b = n >> 5, p = n & 31;
    const size_t sidx = (size_t)n * 4096 + o;
    float s = 0.f;
    #pragma unroll
    for (int part = 0; part < 4; ++part) s += SP[sidx + (size_t)part * 1048576];
    float cp = 1.0f / s;
    const float* ax = cax + o * kNC;
    int lo = 0, hi = kNC;
    while (lo < hi) { int mid = (lo + hi) >> 1; if (ax[mid] < cp) lo = mid + 1; else hi = mid; }
    int bi = lo; if (bi < 1) bi = 1; if (bi > kNC - 1) bi = kNC - 1;
    float x0 = ax[bi - 1], x1 = ax[bi];
    float y0 = E[((size_t)o * kNC + bi - 1) * kP + p];
    float y1 = E[((size_t)o * kNC + bi) * kP + p];
    float invdx = 1.0f / (x1 - x0 + 1e-12f);
    float t = (cp - x0) * invdx;
    float epred = y0 + t * (y1 - y0);
    float dedc = (y1 - y0) * invdx;
    float term = (epred - emax[o * kP + p]) - logZ[o * kP + p];
    XT[sidx] = f2bf(-dedc * cp * cp);

    __shared__ float red[256];
    red[threadIdx.x] = term;
    __syncthreads();
    for (int st = 128; st > 0; st >>= 1) {
        if (threadIdx.x < st) red[threadIdx.x] += red[threadIdx.x + st];
        __syncthreads();
    }
    if (threadIdx.x == 0) atomicAdd(loglike + b, red[0] * (1.0f / 32.0f));
}

// ---------------- grad = J^T contraction + sumsq ----------------
__global__ __launch_bounds__(256) void k_grad(const float* __restrict__ W, const float* __restrict__ c_true,
                       const float* __restrict__ J, float* __restrict__ gout,
                       float* __restrict__ normsq) {
    __shared__ float wsm[8][33];
    __shared__ float red[256];
    const int b = blockIdx.x >> 9;
    const int g0 = (blockIdx.x & 511) << 3;
    {   // coalesced W load: 8 consecutive g per 8 lanes, 32 p rows
        const int p = threadIdx.x >> 3, gq = threadIdx.x & 7;
        const size_t widx = (size_t)(b * 32 + p) * 4096 + g0 + gq;
        float w = 0.f;
        #pragma unroll
        for (int part = 0; part < 4; ++part) w += W[widx + (size_t)part * 1048576];
        float ct = c_true[((size_t)(b << 12) + g0 + gq) * 32 + p];
        wsm[gq][p] = -w / (ct * ct);
    }
    __syncthreads();
    const int gq = threadIdx.x >> 5;   // 0..7
    const int l = threadIdx.x & 31;
    const int g = g0 + gq;
    const float* jrow = J + ((size_t)(b << 12) + g) * (kP * kL) + l;
    float acc = 0.f;
    #pragma unroll
    for (int p = 0; p < 32; ++p) acc += wsm[gq][p] * jrow[p * kL];
    gout[((size_t)(b << 12) + g) * kL + l] = acc;

    red[threadIdx.x] = acc * acc;
    __syncthreads();
    for (int st = 128; st > 0; st >>= 1) {
        if (threadIdx.x < st) red[threadIdx.x] += red[threadIdx.x + st];
        __syncthreads();
    }
    if (threadIdx.x == 0) atomicAdd(normsq + b, red[0]);
}

// ---------------- clip ----------------
__global__ __launch_bounds__(256) void k_clip(float* __restrict__ gout, const float* __restrict__ normsq) {
    const int i = blockIdx.x * 256 + threadIdx.x;
    const int b = i >> 17;
    float norm = sqrtf(normsq[b]);
    float scale = norm > 1000.0f ? 1000.0f / norm : 1.0f;
    gout[i] *= scale;
}

extern "C" void kernel_launch(void* const* d_in, const int* in_sizes, int n_in,
                              void* d_out, int out_size, void* d_ws, size_t ws_size,
                              hipStream_t stream) {
    (void)in_sizes; (void)n_in; (void)out_size; (void)ws_size;
    const float* A      = (const float*)d_in[0];
    const float* c_true = (const float*)d_in[1];
    const float* J      = (const float*)d_in[2];
    const float* E_obs  = (const float*)d_in[3];
    const float* c_axis = (const float*)d_in[4];
    float* out = (float*)d_out;

    char* ws = (char*)d_ws;
    unsigned short* Ah   = (unsigned short*)(ws);                  // 32 MB
    unsigned short* Al   = (unsigned short*)(ws + 33554432);       // 32 MB
    unsigned short* AT   = (unsigned short*)(ws + 67108864);       // 32 MB
    unsigned short* Sh   = (unsigned short*)(ws + 100663296);      // 2 MB
    unsigned short* Sl   = (unsigned short*)(ws + 102760448);      // 2 MB
    unsigned short* XT   = (unsigned short*)(ws + 104857600);      // 2 MB
    float* SP     = (float*)(ws + 106954752);                      // 16 MB (4 k-parts)
    float* Wb     = (float*)(ws + 140509184);                      // 16 MB (4 k-parts)
    float* emax   = (float*)(ws + 174063616);                      // 512 KB
    float* logZ   = (float*)(ws + 174587904);                      // 512 KB
    float* normsq = (float*)(ws + 175112192);                      // 32 B

    hipMemsetAsync(out, 0, 8 * sizeof(float), stream);
    hipMemsetAsync(normsq, 0, 8 * sizeof(float), stream);

    k_prep<<<4096, 256, 0, stream>>>(A, Ah, Al, AT);
    k_strue<<<512, 256, 0, stream>>>(c_true, Sh, Sl);
    k_emax<<<512, 256, 0, stream>>>(E_obs, c_axis, emax, logZ);

    // s_pred^T: fused 3-term split-bf16 (S_hi*A_hi + S_lo*A_hi + S_hi*A_lo)
    k_nt2<1><<<256, 512, 0, stream>>>(Sh, Sl, Ah, Al, SP);

    k_interp<<<4096, 256, 0, stream>>>(SP, E_obs, c_axis, emax, logZ, XT, out);

    // W^T = XT x AT (single bf16 term)
    k_nt2<0><<<256, 512, 0, stream>>>(XT, XT, AT, AT, Wb);

    k_grad<<<4096, 256, 0, stream>>>(Wb, c_true, J, out + 8, normsq);
    k_clip<<<4096, 256, 0, stream>>>(out + 8, normsq);
}